// Round 1
// baseline (256.847 us; speedup 1.0000x reference)
//
#include <hip/hip_runtime.h>
#include <stdint.h>

// Block tensor-train linear: y[b,s,m] = sum_n x[b,s,n] * W[m,n] + bias[m]
// W[i*512 + m1*16+m2, j*512 + n1*16+n2] = sum_r c1[i,j,m1,n1,r]*c2[i,j,r,m2,n2]
// Strategy: build W once in bf16 (8 MB of d_ws, 67 MFLOP), then bf16 MFMA GEMM
// (M=16384, N=2048, K=2048; NT layout: both operands row-major with K contiguous).

typedef __attribute__((ext_vector_type(8))) __bf16 bf16x8;
typedef __attribute__((ext_vector_type(4))) float f32x4;
typedef __attribute__((ext_vector_type(4))) unsigned short us4;

#define M_TOT 16384
#define N_TOT 2048
#define K_TOT 2048
#define BM 128
#define BN 128
#define BK 32
#define NKT (K_TOT / BK)  // 64 K-steps

__device__ __forceinline__ unsigned short f2bf(float f) {
  union { float f; unsigned u; } v; v.f = f;
  unsigned u = v.u;
  u += 0x7FFFu + ((u >> 16) & 1u);   // round-to-nearest-even
  return (unsigned short)(u >> 16);
}

// async global->LDS, 16B per lane; lds dest = wave-uniform base + lane*16
__device__ __forceinline__ void gld_lds16(const void* g, void* l) {
  __builtin_amdgcn_global_load_lds(
      (const __attribute__((address_space(1))) unsigned int*)g,
      (__attribute__((address_space(3))) unsigned int*)l, 16, 0, 0);
}

// ---------------------------------------------------------------------------
// Kernel 1: reconstruct W in bf16. One thread per element, 16-term dot.
// cores1 [4,4,32,32,16] (r contiguous), cores2 [4,4,16,16,16] (r stride 256).
// All core data ~1.3 MB -> L2-resident; negligible runtime.
// ---------------------------------------------------------------------------
__global__ void build_w_kernel(const float* __restrict__ c1,
                               const float* __restrict__ c2,
                               unsigned short* __restrict__ W) {
  int idx = blockIdx.x * 256 + threadIdx.x;      // n*2048 + k
  int k = idx & (K_TOT - 1);
  int n = idx >> 11;
  int i = n >> 9, ob = n & 511;
  int m1 = ob >> 4, m2 = ob & 15;
  int j = k >> 9, ib = k & 511;
  int n1 = ib >> 4, n2 = ib & 15;
  const float* a = c1 + ((((i * 4 + j) * 32 + m1) * 32 + n1) * 16);
  const float* b = c2 + ((i * 4 + j) * 4096 + m2 * 16 + n2);
  float s = 0.f;
#pragma unroll
  for (int r = 0; r < 16; ++r) s += a[r] * b[r * 256];
  W[idx] = f2bf(s);
}

// ---------------------------------------------------------------------------
// Kernel 2: C = X * W^T + bias.  128x128 tile, BK=32, 4 waves (2x2), each wave
// a 64x64 sub-tile as 4x4 frags of mfma_f32_16x16x32_bf16. B via
// global_load_lds(16B); A reg-staged (fp32->bf16 cvt) with issue-early/
// write-late split so HBM latency hides under MFMA. Double-buffered LDS.
// ---------------------------------------------------------------------------
__global__ __launch_bounds__(256, 2) void gemm_bias_kernel(
    const float* __restrict__ X, const unsigned short* __restrict__ W,
    const float* __restrict__ bias, float* __restrict__ Y) {
  __shared__ __align__(16) unsigned short Alds[2][BM * BK];  // 2 x 8 KB
  __shared__ __align__(16) unsigned short Blds[2][BN * BK];  // 2 x 8 KB

  const int tid = threadIdx.x;
  const int lane = tid & 63;
  const int wid = tid >> 6;
  const int wm = wid >> 1, wn = wid & 1;  // 2x2 wave grid

  // bijective XCD swizzle: 2048 wgs, 8 XCDs -> each XCD a contiguous 256-wg
  // chunk => A-panel (1 MB) L2-resident per XCD while its 16 n-tiles run.
  int bid = blockIdx.x;
  int wgid = (bid & 7) * ((M_TOT / BM) * (N_TOT / BN) / 8) + (bid >> 3);
  const int mblk = wgid >> 4;          // / (N_TOT/BN)
  const int nblk = wgid & 15;
  const int m0 = mblk * BM, n0 = nblk * BN;

  // A staging: pass p covers rows p*32..p*32+31; thread -> (row, 4 fp32)
  const int ar = tid >> 3;            // 0..31
  const int ac = (tid & 7) * 4;       // 0..28
  // B staging: issue i, lane chunk of 8 bf16 along K
  const int brow = (tid >> 2);        // (i*256+tid)/4 = i*64 + tid/4
  const int bcol = (tid & 3) * 8;

  f32x4 acc[4][4];
#pragma unroll
  for (int m = 0; m < 4; ++m)
#pragma unroll
    for (int n = 0; n < 4; ++n) acc[m][n] = {0.f, 0.f, 0.f, 0.f};

  f32x4 apre[4];

  auto stageA_load = [&](int k0) {
#pragma unroll
    for (int p = 0; p < 4; ++p)
      apre[p] = *(const f32x4*)&X[(size_t)(m0 + p * 32 + ar) * K_TOT + k0 + ac];
  };
  auto stageA_write = [&](int buf) {
#pragma unroll
    for (int p = 0; p < 4; ++p) {
      us4 h;
      h[0] = f2bf(apre[p][0]); h[1] = f2bf(apre[p][1]);
      h[2] = f2bf(apre[p][2]); h[3] = f2bf(apre[p][3]);
      *(us4*)&Alds[buf][(p * 32 + ar) * BK + ac] = h;
    }
  };
  auto stageB = [&](int k0, int buf) {
#pragma unroll
    for (int i = 0; i < 2; ++i) {
      const unsigned short* g = &W[(size_t)(n0 + i * 64 + brow) * K_TOT + k0 + bcol];
      unsigned short* l = &Blds[buf][i * 2048 + wid * 512];  // wave-uniform base
      gld_lds16(g, l);
    }
  };
  auto compute = [&](int buf) {
    const unsigned short* Ab = &Alds[buf][(wm * 64 + (lane & 15)) * BK + (lane >> 4) * 8];
    const unsigned short* Bb = &Blds[buf][(wn * 64 + (lane & 15)) * BK + (lane >> 4) * 8];
    bf16x8 af[4], bfv[4];
#pragma unroll
    for (int m = 0; m < 4; ++m) af[m] = *(const bf16x8*)(Ab + m * 16 * BK);
#pragma unroll
    for (int n = 0; n < 4; ++n) bfv[n] = *(const bf16x8*)(Bb + n * 16 * BK);
#pragma unroll
    for (int m = 0; m < 4; ++m)
#pragma unroll
      for (int n = 0; n < 4; ++n)
        acc[m][n] = __builtin_amdgcn_mfma_f32_16x16x32_bf16(af[m], bfv[n],
                                                            acc[m][n], 0, 0, 0);
  };

  // prologue: stage tile 0 into buf 0
  stageA_load(0);
  stageB(0, 0);
  stageA_write(0);
  __syncthreads();

  for (int kt = 0; kt < NKT; ++kt) {
    const int cur = kt & 1, nxt = cur ^ 1;
    if (kt + 1 < NKT) {
      stageA_load((kt + 1) * BK);   // issue A loads early (latency under MFMA)
      stageB((kt + 1) * BK, nxt);   // async B -> LDS
    }
    compute(cur);
    if (kt + 1 < NKT) stageA_write(nxt);  // cvt + ds_write after compute
    __syncthreads();                       // drains vmcnt/lgkmcnt
  }

  // epilogue: C/D layout col = lane&15, row = (lane>>4)*4 + j  [m89/m91]
  const int col = lane & 15;
  const int rb = (lane >> 4) * 4;
#pragma unroll
  for (int n = 0; n < 4; ++n) {
    const int gc = n0 + wn * 64 + n * 16 + col;
    const float bv = bias[gc];
#pragma unroll
    for (int m = 0; m < 4; ++m) {
#pragma unroll
      for (int j = 0; j < 4; ++j) {
        const int gr = m0 + wm * 64 + m * 16 + rb + j;
        Y[(size_t)gr * N_TOT + gc] = acc[m][n][j] + bv;
      }
    }
  }
}

extern "C" void kernel_launch(void* const* d_in, const int* in_sizes, int n_in,
                              void* d_out, int out_size, void* d_ws, size_t ws_size,
                              hipStream_t stream) {
  const float* x     = (const float*)d_in[0];
  const float* c1    = (const float*)d_in[1];
  const float* c2    = (const float*)d_in[2];
  const float* bias  = (const float*)d_in[3];
  float* y           = (float*)d_out;
  unsigned short* W  = (unsigned short*)d_ws;  // 2048*2048 bf16 = 8 MB

  build_w_kernel<<<(N_TOT * K_TOT) / 256, 256, 0, stream>>>(c1, c2, W);
  gemm_bias_kernel<<<(M_TOT / BM) * (N_TOT / BN), 256, 0, stream>>>(x, W, bias, y);
}

// Round 2
// 185.698 us; speedup vs baseline: 1.3831x; 1.3831x over previous
//
#include <hip/hip_runtime.h>
#include <stdint.h>

// y[b,s,m] = sum_n x[b,s,n] * W[m,n] + bias[m], W from TT cores (bf16, built once).
// Pipeline: build_w (8 MB bf16) -> convert_x (fp32->bf16, 64 MB) -> 8-phase 256^2 GEMM.

typedef __attribute__((ext_vector_type(8))) __bf16 bf16x8;
typedef __attribute__((ext_vector_type(4))) float f32x4;
typedef __attribute__((ext_vector_type(4))) unsigned short us4;
typedef __attribute__((ext_vector_type(8))) unsigned short us8;

#define M_TOT 16384
#define N_TOT 2048
#define K_TOT 2048

__device__ __forceinline__ unsigned short f2bf(float f) {
  union { float f; unsigned u; } v; v.f = f;
  unsigned u = v.u;
  u += 0x7FFFu + ((u >> 16) & 1u);   // RNE
  return (unsigned short)(u >> 16);
}

__device__ __forceinline__ void gld_lds16(const void* g, void* l) {
  __builtin_amdgcn_global_load_lds(
      (const __attribute__((address_space(1))) unsigned int*)g,
      (__attribute__((address_space(3))) unsigned int*)l, 16, 0, 0);
}

#define BARRIER() __builtin_amdgcn_s_barrier()
#define WAIT_LGKM0() asm volatile("s_waitcnt lgkmcnt(0)" ::: "memory")
#define WAIT_VM0() asm volatile("s_waitcnt vmcnt(0)" ::: "memory")
#define WAIT_VM4() asm volatile("s_waitcnt vmcnt(4)" ::: "memory")

// ---------------------------------------------------------------------------
// Kernel 1: reconstruct W (bf16). W[n,k], n=out (2048), k=in (2048).
// ---------------------------------------------------------------------------
__global__ void build_w_kernel(const float* __restrict__ c1,
                               const float* __restrict__ c2,
                               unsigned short* __restrict__ W) {
  int idx = blockIdx.x * 256 + threadIdx.x;      // n*2048 + k
  int k = idx & (K_TOT - 1);
  int n = idx >> 11;
  int i = n >> 9, ob = n & 511;
  int m1 = ob >> 4, m2 = ob & 15;
  int j = k >> 9, ib = k & 511;
  int n1 = ib >> 4, n2 = ib & 15;
  const float* a = c1 + ((((i * 4 + j) * 32 + m1) * 32 + n1) * 16);
  const float* b = c2 + ((i * 4 + j) * 4096 + m2 * 16 + n2);
  float s = 0.f;
#pragma unroll
  for (int r = 0; r < 16; ++r) s += a[r] * b[r * 256];
  W[idx] = f2bf(s);
}

// ---------------------------------------------------------------------------
// Kernel 2: X fp32 -> bf16 (vectorized, 8 elems/thread/iter)
// ---------------------------------------------------------------------------
__global__ void convert_x_kernel(const float* __restrict__ X,
                                 unsigned short* __restrict__ Xb) {
  const size_t n8 = (size_t)M_TOT * K_TOT / 8;
  const size_t stride = (size_t)gridDim.x * blockDim.x;
  for (size_t i = (size_t)blockIdx.x * blockDim.x + threadIdx.x; i < n8; i += stride) {
    f32x4 a = ((const f32x4*)X)[i * 2];
    f32x4 b = ((const f32x4*)X)[i * 2 + 1];
    us8 h;
    h[0] = f2bf(a[0]); h[1] = f2bf(a[1]); h[2] = f2bf(a[2]); h[3] = f2bf(a[3]);
    h[4] = f2bf(b[0]); h[5] = f2bf(b[1]); h[6] = f2bf(b[2]); h[7] = f2bf(b[3]);
    ((us8*)Xb)[i] = h;
  }
}

// ---------------------------------------------------------------------------
// Kernel 3: 8-phase 256x256 bf16 GEMM, BK=64, 512 thr (8 waves 2Mx4N).
// LDS 128 KiB: [buf2][sect4][128x64 bf16]; sect 0/1 = A halves, 2/3 = B halves.
// XOR swizzle: 16B block b of row r stored at block b^(r&7). gload_lds writes
// linearly, so the *global source* col is pre-inverse-swizzled; ds_read applies
// the same XOR. vmcnt counted (4), never 0 in steady state.
// ---------------------------------------------------------------------------
__global__ __launch_bounds__(512, 2) void gemm8p_kernel(
    const unsigned short* __restrict__ Xb, const unsigned short* __restrict__ W,
    const float* __restrict__ bias, float* __restrict__ Y) {
  __shared__ __align__(16) unsigned short lds[2][4][128 * 64];

  const int tid = threadIdx.x;
  const int lane = tid & 63;
  const int wid = tid >> 6;
  const int wm = wid >> 2, wn = wid & 3;     // 2 x 4 wave grid

  // bijective XCD swizzle: 512 wgs, 8 XCDs, 64-wg chunks; within a chunk,
  // 8 consecutive wgs share an mblk (A panel stays hot in the XCD's L2).
  const int bid = blockIdx.x;
  const int xcd = bid & 7, loc = bid >> 3;
  const int mblk = xcd * 8 + (loc >> 3);     // 0..63
  const int nblk = loc & 7;                  // 0..7
  const int m0 = mblk * 256, n0 = nblk * 256;

  // fragment read addressing
  const int fr = lane & 15, g = lane >> 4;
  const int swz = fr & 7;
  const int blkB0 = ((0 + g) ^ swz) * 16;    // ksub=0 byte offset of 16B block
  const int blkB1 = ((4 + g) ^ swz) * 16;    // ksub=1
  const int arow = fr * 128;                 // + m*2048 bytes
  const int brow = ((wn & 1) * 64 + fr) * 128;  // + n*2048 bytes

  // staging source mapping (inverse swizzle on global col)
  const int sr = tid >> 3;                           // row within 64-row issue
  const int sc = ((tid & 7) ^ (sr & 7)) * 8;         // bf16 col offset

  auto stageA = [&](int half, int buf, int kt) {
    const unsigned short* base = Xb + (size_t)(m0 + half * 128) * K_TOT + kt * 64 + sc;
#pragma unroll
    for (int i = 0; i < 2; ++i)
      gld_lds16(base + (size_t)(i * 64 + sr) * K_TOT,
                &lds[buf][half][i * 4096 + wid * 512]);
  };
  auto stageB = [&](int half, int buf, int kt) {
    const unsigned short* base = W + (size_t)(n0 + half * 128) * K_TOT + kt * 64 + sc;
#pragma unroll
    for (int i = 0; i < 2; ++i)
      gld_lds16(base + (size_t)(i * 64 + sr) * K_TOT,
                &lds[buf][2 + half][i * 4096 + wid * 512]);
  };
  auto ldA = [&](int c, int m, int ks) -> bf16x8 {
    const char* p = (const char*)&lds[c][wm][0] + arow + m * 2048 + (ks ? blkB1 : blkB0);
    return *(const bf16x8*)p;
  };
  auto ldB = [&](int c, int n, int ks) -> bf16x8 {
    const char* p = (const char*)&lds[c][2 + (wn >> 1)][0] + brow + n * 2048 + (ks ? blkB1 : blkB0);
    return *(const bf16x8*)p;
  };

  f32x4 acc[8][4];
#pragma unroll
  for (int m = 0; m < 8; ++m)
#pragma unroll
    for (int n = 0; n < 4; ++n) acc[m][n] = {0.f, 0.f, 0.f, 0.f};

  const int NT = K_TOT / 64;  // 32 K-tiles

  // prologue: tile0 fully (buf0) + B halves of tile1 (buf1)
  stageA(0, 0, 0); stageA(1, 0, 0);
  stageB(0, 0, 0); stageB(1, 0, 0);
  stageB(0, 1, 1); stageB(1, 1, 1);
  WAIT_VM0();
  BARRIER();

  bf16x8 bq[4][2];
  for (int t = 0; t < NT; ++t) {
    const int c = t & 1;
#pragma unroll
    for (int q = 0; q < 4; ++q) {
      // --- ds reads for this phase's MFMA quadrant ---
      bf16x8 a0 = ldA(c, 2 * q, 0);
      bf16x8 a0k = ldA(c, 2 * q, 1);
      bf16x8 a1 = ldA(c, 2 * q + 1, 0);
      bf16x8 a1k = ldA(c, 2 * q + 1, 1);
      if (q == 0) {
#pragma unroll
        for (int n = 0; n < 4; ++n) {
          bq[n][0] = ldB(c, n, 0);
          bq[n][1] = ldB(c, n, 1);
        }
      }
      // --- stage one half-tile ---
      if (q == 0 && t + 1 < NT) stageA(0, c ^ 1, t + 1);
      if (q == 1 && t + 1 < NT) stageA(1, c ^ 1, t + 1);
      if (q == 2 && t + 2 < NT) stageB(0, c, t + 2);
      if (q == 3) {
        if (t + 2 < NT) { stageB(1, c, t + 2); WAIT_VM4(); }
        else            { WAIT_VM0(); }   // pipeline drain at the tail
      }
      BARRIER();
      WAIT_LGKM0();
      __builtin_amdgcn_s_setprio(1);
#pragma unroll
      for (int n = 0; n < 4; ++n) {
        acc[2 * q][n] = __builtin_amdgcn_mfma_f32_16x16x32_bf16(a0, bq[n][0], acc[2 * q][n], 0, 0, 0);
        acc[2 * q][n] = __builtin_amdgcn_mfma_f32_16x16x32_bf16(a0k, bq[n][1], acc[2 * q][n], 0, 0, 0);
        acc[2 * q + 1][n] = __builtin_amdgcn_mfma_f32_16x16x32_bf16(a1, bq[n][0], acc[2 * q + 1][n], 0, 0, 0);
        acc[2 * q + 1][n] = __builtin_amdgcn_mfma_f32_16x16x32_bf16(a1k, bq[n][1], acc[2 * q + 1][n], 0, 0, 0);
      }
      __builtin_amdgcn_s_setprio(0);
      BARRIER();
    }
  }

  // epilogue: D layout col=lane&15, row=(lane>>4)*4+j  [verified round 1]
  const int rb4 = g * 4;
#pragma unroll
  for (int n = 0; n < 4; ++n) {
    const int gc = n0 + wn * 64 + n * 16 + fr;
    const float bv = bias[gc];
#pragma unroll
    for (int m = 0; m < 8; ++m) {
#pragma unroll
      for (int j = 0; j < 4; ++j) {
        const int gr = m0 + wm * 128 + m * 16 + rb4 + j;
        Y[(size_t)gr * N_TOT + gc] = acc[m][n][j] + bv;
      }
    }
  }
}

// ---------------------------------------------------------------------------
// Fallback GEMM (verified round 1): 128^2 tile, in-kernel fp32->bf16 A staging.
// Used only if ws_size < 72 MB.
// ---------------------------------------------------------------------------
__global__ __launch_bounds__(256, 2) void gemm_fb_kernel(
    const float* __restrict__ X, const unsigned short* __restrict__ W,
    const float* __restrict__ bias, float* __restrict__ Y) {
  __shared__ __align__(16) unsigned short Alds[2][128 * 32];
  __shared__ __align__(16) unsigned short Blds[2][128 * 32];
  const int tid = threadIdx.x;
  const int lane = tid & 63;
  const int wid = tid >> 6;
  const int wm = wid >> 1, wn = wid & 1;
  int bid = blockIdx.x;
  int wgid = (bid & 7) * (2048 / 8) + (bid >> 3);
  const int m0 = (wgid >> 4) * 128, n0 = (wgid & 15) * 128;
  const int ar = tid >> 3, ac = (tid & 7) * 4;
  const int br = (tid >> 2), bc = (tid & 3) * 8;
  f32x4 acc[4][4];
#pragma unroll
  for (int m = 0; m < 4; ++m)
#pragma unroll
    for (int n = 0; n < 4; ++n) acc[m][n] = {0.f, 0.f, 0.f, 0.f};
  f32x4 apre[4];
  auto stA_l = [&](int k0) {
#pragma unroll
    for (int p = 0; p < 4; ++p)
      apre[p] = *(const f32x4*)&X[(size_t)(m0 + p * 32 + ar) * K_TOT + k0 + ac];
  };
  auto stA_w = [&](int buf) {
#pragma unroll
    for (int p = 0; p < 4; ++p) {
      us4 h;
      h[0] = f2bf(apre[p][0]); h[1] = f2bf(apre[p][1]);
      h[2] = f2bf(apre[p][2]); h[3] = f2bf(apre[p][3]);
      *(us4*)&Alds[buf][(p * 32 + ar) * 32 + ac] = h;
    }
  };
  auto stB = [&](int k0, int buf) {
#pragma unroll
    for (int i = 0; i < 2; ++i)
      gld_lds16(&W[(size_t)(n0 + i * 64 + br) * K_TOT + k0 + bc],
                &Blds[buf][i * 2048 + wid * 512]);
  };
  auto comp = [&](int buf) {
    const unsigned short* Ab = &Alds[buf][(wm * 64 + (lane & 15)) * 32 + (lane >> 4) * 8];
    const unsigned short* Bb = &Blds[buf][(wn * 64 + (lane & 15)) * 32 + (lane >> 4) * 8];
    bf16x8 af[4], bfv[4];
#pragma unroll
    for (int m = 0; m < 4; ++m) af[m] = *(const bf16x8*)(Ab + m * 16 * 32);
#pragma unroll
    for (int n = 0; n < 4; ++n) bfv[n] = *(const bf16x8*)(Bb + n * 16 * 32);
#pragma unroll
    for (int m = 0; m < 4; ++m)
#pragma unroll
      for (int n = 0; n < 4; ++n)
        acc[m][n] = __builtin_amdgcn_mfma_f32_16x16x32_bf16(af[m], bfv[n], acc[m][n], 0, 0, 0);
  };
  stA_l(0); stB(0, 0); stA_w(0);
  __syncthreads();
  for (int kt = 0; kt < 64; ++kt) {
    const int cur = kt & 1, nxt = cur ^ 1;
    if (kt + 1 < 64) { stA_l((kt + 1) * 32); stB((kt + 1) * 32, nxt); }
    comp(cur);
    if (kt + 1 < 64) stA_w(nxt);
    __syncthreads();
  }
  const int col = lane & 15, rb = (lane >> 4) * 4;
#pragma unroll
  for (int n = 0; n < 4; ++n) {
    const int gc = n0 + wn * 64 + n * 16 + col;
    const float bv = bias[gc];
#pragma unroll
    for (int m = 0; m < 4; ++m)
#pragma unroll
      for (int j = 0; j < 4; ++j)
        Y[(size_t)(m0 + wm * 64 + m * 16 + rb + j) * N_TOT + gc] = acc[m][n][j] + bv;
  }
}

extern "C" void kernel_launch(void* const* d_in, const int* in_sizes, int n_in,
                              void* d_out, int out_size, void* d_ws, size_t ws_size,
                              hipStream_t stream) {
  const float* x    = (const float*)d_in[0];
  const float* c1   = (const float*)d_in[1];
  const float* c2   = (const float*)d_in[2];
  const float* bias = (const float*)d_in[3];
  float* y          = (float*)d_out;
  unsigned short* W = (unsigned short*)d_ws;                    // 8 MB
  unsigned short* Xb = (unsigned short*)((char*)d_ws + (8u << 20));  // 64 MB

  build_w_kernel<<<(N_TOT * K_TOT) / 256, 256, 0, stream>>>(c1, c2, W);

  const size_t need = (size_t)(8u << 20) + (size_t)M_TOT * K_TOT * 2;
  if (ws_size >= need) {
    convert_x_kernel<<<2048, 256, 0, stream>>>(x, Xb);
    gemm8p_kernel<<<(M_TOT / 256) * (N_TOT / 256), 512, 0, stream>>>(Xb, W, bias, y);
  } else {
    gemm_fb_kernel<<<(M_TOT / 128) * (N_TOT / 128), 256, 0, stream>>>(x, W, bias, y);
  }
}